// Round 3
// baseline (211.561 us; speedup 1.0000x reference)
//
#include <hip/hip_runtime.h>
#include <math.h>

typedef __attribute__((ext_vector_type(8))) short bf16x8;
typedef __attribute__((ext_vector_type(4))) float f32x4;

__device__ __forceinline__ unsigned short f2bf(float f) {
    unsigned u = __builtin_bit_cast(unsigned, f);
    u += 0x7FFF + ((u >> 16) & 1);          // RNE
    return (unsigned short)(u >> 16);
}
__device__ __forceinline__ float bf2f(unsigned short h) {
    unsigned u = ((unsigned)h) << 16;
    return __builtin_bit_cast(float, u);
}

// Packed-weight offsets inside Wb (bf16 elements), W3..W11 cumulative
#define O_W3 0
#define O_W4 6144
#define O_W5 18432
#define O_W6 30720
#define O_W7 55296
#define O_W8 153600
#define O_W9 546816
#define O_W10 1333248
#define O_W11 2119680

// ============================================================================
// MFMA helpers (verified R9/R11/R12 of previous session)
// ============================================================================
template<int CIN>
__device__ __forceinline__ void mfma_tile(
    const unsigned short* a0, const unsigned short* a1,
    const unsigned short* b0p, const unsigned short* b1p,
    f32x4& acc0, f32x4& acc1)
{
#pragma unroll
    for (int k = 0; k < CIN; k += 32) {
        bf16x8 A0 = __builtin_bit_cast(bf16x8, *(const float4*)(const void*)(a0 + k));
        bf16x8 A1 = __builtin_bit_cast(bf16x8, *(const float4*)(const void*)(a1 + k));
        bf16x8 B0 = __builtin_bit_cast(bf16x8, *(const float4*)(const void*)(b0p + k));
        bf16x8 B1 = __builtin_bit_cast(bf16x8, *(const float4*)(const void*)(b1p + k));
        acc0 = __builtin_amdgcn_mfma_f32_16x16x32_bf16(A0, B0, acc0, 0, 0, 0);
        acc1 = __builtin_amdgcn_mfma_f32_16x16x32_bf16(A1, B1, acc1, 0, 0, 0);
    }
}

__device__ __forceinline__ void epilogue_store(
    unsigned short* dst, const f32x4& acc0, const f32x4& acc1,
    const float* bias, int fbase, int s0, int s1)
{
    unsigned short o[4];
#pragma unroll
    for (int r = 0; r < 4; ++r) {
        float v = fmaxf(fmaxf(acc0[r] + bias[(fbase + r) * 3 + s0],
                              acc1[r] + bias[(fbase + r) * 3 + s1]), 0.f);
        o[r] = f2bf(v);
    }
    *(ushort4*)dst = make_ushort4(o[0], o[1], o[2], o[3]);
}

// ============================================================================
// K0: pack W3..W11 fp32 -> bf16 into Wb. 256 blocks x 256 thr.
// ============================================================================
struct PackParams { const float* Wsrc[9]; unsigned short* Wb; };

__global__ __launch_bounds__(256) void pack_w_kernel(PackParams P)
{
    int gt = blockIdx.x * 256 + threadIdx.x;
    const int we[9] = {6144, 12288, 12288, 24576, 98304, 393216, 786432, 786432, 1572864};
    int off = 0;
#pragma unroll
    for (int li = 0; li < 9; ++li) {
        const float4* src = (const float4*)P.Wsrc[li];
        ushort4* dst = (ushort4*)(P.Wb + off);
        int n4 = we[li] >> 2;
        for (int i = gt; i < n4; i += 65536) {
            float4 w = src[i];
            dst[i] = make_ushort4(f2bf(w.x), f2bf(w.y), f2bf(w.z), f2bf(w.w));
        }
        off += we[li];
    }
}

// ============================================================================
// K1: fused L1..L7. 128 blocks (bg 0..7 x sl 0..15) x 512 threads.
// MFMA A-operands (weights) read DIRECTLY from packed global bf16 Wb
// (L2-hot: all blocks share ~210 KB). B-operands flow through an LDS chain.
// 8 phases, 7 barriers. Writes X8[pos16][b128][256] bf16.
// ============================================================================
struct FusedParams {
    const float* x;
    const float* W1; const float* B1; const int* S1;
    const float* W2; const float* B2; const int* S2;
    const float* Bl[9];            // B3..B11
    const int*   Sl[9];            // S3..S11
    const unsigned short* Wb;      // packed bf16 W3..W11
    unsigned short* X8;            // out: [16][128][256] bf16
};

// Arena (bytes, 16B aligned). Lifetimes:
//  XS   [16][3][132] f32   : stage -> L1
//  L1O  [64][16][8]  ush   : L1 -> L2
//  WSM  W1/B1/W2/B2  f32   : stage -> L2
//  L2O  [32][16][40] ush   : L2 -> L3
//  L3O  [16][16][72] ush   : L3 -> L4   (over XS+L1O, dead)
//  L4O  [8][16][72]  ush   : L4 -> L5   (over L2O, dead)
//  L5O  [4][16][72]  ush   : L5 -> L6   (over L3O, dead)
//  L6O  [2][16][136] ush   : L6 -> L7   (over L4O, dead)
#define A_XS   0        // 25344 B
#define A_L1O  25344    // 16384 B
#define A_WSM  41728    //  3840 B
#define A_L2O  45568    // 40960 B  (end 86528)
#define A_L3O  0        // 36864 B
#define A_L4O  45568    // 18432 B
#define A_L5O  0        //  9216 B
#define A_L6O  45568    //  8704 B
#define ARENA_BYTES 86528

__global__ __launch_bounds__(512) void fused17_kernel(FusedParams P)
{
    __shared__ __align__(16) char arena[ARENA_BYTES];

    const int tid  = threadIdx.x;
    const int bg   = blockIdx.x >> 4;      // 0..7  (batch b = bg*16 + 0..15)
    const int sl   = blockIdx.x & 15;      // 0..15 (input pos slice)
    const int lane = tid & 63;
    const int wv   = tid >> 6;             // 0..7
    const int c    = lane & 15, q = lane >> 4;

    const unsigned short* W3b = P.Wb + O_W3;
    const unsigned short* W4b = P.Wb + O_W4;
    const unsigned short* W5b = P.Wb + O_W5;
    const unsigned short* W6b = P.Wb + O_W6;
    const unsigned short* W7b = P.Wb + O_W7;

    // ---- stage x slice + L1/L2 weights ----
    {
        float* xsf = (float*)(arena + A_XS);
        const float* xg = P.x + (size_t)(bg * 16) * 6144 + sl * 128;
        for (int i = tid; i < 6144; i += 512) {
            int b = i / 384;
            int r = i - b * 384;
            int cc = r >> 7, p = r & 127;
            xsf[b * 396 + cc * 132 + p] = xg[(size_t)b * 6144 + cc * 2048 + p];
        }
        float* wsm = (float*)(arena + A_WSM);
        for (int i = tid; i < 960; i += 512) {
            float v;
            if (i < 72)       v = P.W1[i];
            else if (i < 96)  v = P.B1[i - 72];
            else if (i < 864) v = P.W2[i - 96];
            else              v = P.B2[i - 864];
            wsm[i] = v;
        }
    }
    __syncthreads();

    // ---- L1 (cf=8, cin=3, VALU): 64 out pos x 16 b ----
    {
        const float* xsf = (const float*)(arena + A_XS);
        const float* wl1 = (const float*)(arena + A_WSM);
        const float* bl1 = wl1 + 72;
        unsigned short* L1o = (unsigned short*)(arena + A_L1O);
        for (int i = tid; i < 1024; i += 512) {
            int n = i >> 4, b = i & 15;
            int np1 = sl * 64 + n;
            int s0 = P.S1[2 * np1], s1 = P.S1[2 * np1 + 1];
            const float* xb0 = xsf + b * 396 + 2 * n;
            float c0x = xb0[0],   c0y = xb0[1];
            float c1x = xb0[132], c1y = xb0[133];
            float c2x = xb0[264], c2y = xb0[265];
            unsigned short o[8];
#pragma unroll
            for (int f = 0; f < 8; ++f) {
                int r0 = f * 3 + s0, r1 = f * 3 + s1;
                float z0 = fmaf(wl1[r0*3+2], c2x, fmaf(wl1[r0*3+1], c1x, fmaf(wl1[r0*3+0], c0x, bl1[r0])));
                float z1 = fmaf(wl1[r1*3+2], c2y, fmaf(wl1[r1*3+1], c1y, fmaf(wl1[r1*3+0], c0y, bl1[r1])));
                o[f] = f2bf(fmaxf(fmaxf(z0, z1), 0.f));
            }
            unsigned short* dst = L1o + (n * 16 + b) * 8;
            *(ushort4*)dst       = make_ushort4(o[0], o[1], o[2], o[3]);
            *(ushort4*)(dst + 4) = make_ushort4(o[4], o[5], o[6], o[7]);
        }
    }
    __syncthreads();

    // ---- L2 (cf=32, cin=8, VALU): 32 out pos x 16 b = 512 items ----
    {
        const float* wl2 = (const float*)(arena + A_WSM) + 96;
        const float* bl2 = (const float*)(arena + A_WSM) + 864;
        const unsigned short* L1o = (const unsigned short*)(arena + A_L1O);
        unsigned short* L2o = (unsigned short*)(arena + A_L2O);
        {
            int i = tid;  // exactly 512 items
            int n = i >> 4, b = i & 15;
            int np2 = sl * 32 + n;
            int s0 = P.S2[2 * np2], s1 = P.S2[2 * np2 + 1];
            const unsigned short* r0 = L1o + ((2 * n) * 16 + b) * 8;
            const unsigned short* r1 = L1o + ((2 * n + 1) * 16 + b) * 8;
            float xa[8], xb2[8];
            {
                ushort4 u0 = *(const ushort4*)r0, u1 = *(const ushort4*)(r0 + 4);
                ushort4 v0 = *(const ushort4*)r1, v1 = *(const ushort4*)(r1 + 4);
                xa[0]=bf2f(u0.x); xa[1]=bf2f(u0.y); xa[2]=bf2f(u0.z); xa[3]=bf2f(u0.w);
                xa[4]=bf2f(u1.x); xa[5]=bf2f(u1.y); xa[6]=bf2f(u1.z); xa[7]=bf2f(u1.w);
                xb2[0]=bf2f(v0.x); xb2[1]=bf2f(v0.y); xb2[2]=bf2f(v0.z); xb2[3]=bf2f(v0.w);
                xb2[4]=bf2f(v1.x); xb2[5]=bf2f(v1.y); xb2[6]=bf2f(v1.z); xb2[7]=bf2f(v1.w);
            }
            unsigned short o[32];
#pragma unroll
            for (int f = 0; f < 32; ++f) {
                const float* w0 = &wl2[(f * 3 + s0) * 8];
                const float* w1 = &wl2[(f * 3 + s1) * 8];
                float z0 = bl2[f * 3 + s0], z1 = bl2[f * 3 + s1];
#pragma unroll
                for (int k = 0; k < 8; ++k) {
                    z0 = fmaf(w0[k], xa[k], z0);
                    z1 = fmaf(w1[k], xb2[k], z1);
                }
                o[f] = f2bf(fmaxf(fmaxf(z0, z1), 0.f));
            }
            unsigned short* dst = L2o + (n * 16 + b) * 40;
#pragma unroll
            for (int i2 = 0; i2 < 8; ++i2)
                *(ushort4*)(dst + 4 * i2) = make_ushort4(o[4*i2], o[4*i2+1], o[4*i2+2], o[4*i2+3]);
        }
    }
    __syncthreads();

    // ---- L3 (cf=64, cin=32, MFMA): 16 pos x 4 ftiles = 64 tasks ----
    {
        const unsigned short* L2o = (const unsigned short*)(arena + A_L2O);
        unsigned short* L3o = (unsigned short*)(arena + A_L3O);
        const int* S3 = P.Sl[0]; const float* B3 = P.Bl[0];
#pragma unroll 2
        for (int t = wv; t < 64; t += 8) {
            int n3 = t >> 2, ft = t & 3;
            int np = sl * 16 + n3;
            int s0 = __builtin_amdgcn_readfirstlane(S3[2 * np]);
            int s1 = __builtin_amdgcn_readfirstlane(S3[2 * np + 1]);
            int f0 = ft * 16;
            const unsigned short* a0 = W3b + ((f0 + c) * 3 + s0) * 32 + q * 8;
            const unsigned short* a1 = W3b + ((f0 + c) * 3 + s1) * 32 + q * 8;
            const unsigned short* bp0 = L2o + ((2 * n3) * 16 + c) * 40 + q * 8;
            const unsigned short* bp1 = L2o + ((2 * n3 + 1) * 16 + c) * 40 + q * 8;
            f32x4 acc0 = {0.f,0.f,0.f,0.f}, acc1 = {0.f,0.f,0.f,0.f};
            mfma_tile<32>(a0, a1, bp0, bp1, acc0, acc1);
            epilogue_store(L3o + (n3 * 16 + c) * 72 + f0 + q * 4,
                           acc0, acc1, B3, f0 + q * 4, s0, s1);
        }
    }
    __syncthreads();

    // ---- L4 (cf=64, cin=64): 8 pos x 4 ftiles = 32 tasks ----
    {
        const unsigned short* L3o = (const unsigned short*)(arena + A_L3O);
        unsigned short* L4o = (unsigned short*)(arena + A_L4O);
        const int* S4 = P.Sl[1]; const float* B4 = P.Bl[1];
#pragma unroll 2
        for (int t = wv; t < 32; t += 8) {
            int n4 = t >> 2, ft = t & 3;
            int np = sl * 8 + n4;
            int s0 = __builtin_amdgcn_readfirstlane(S4[2 * np]);
            int s1 = __builtin_amdgcn_readfirstlane(S4[2 * np + 1]);
            int f0 = ft * 16;
            const unsigned short* a0 = W4b + ((f0 + c) * 3 + s0) * 64 + q * 8;
            const unsigned short* a1 = W4b + ((f0 + c) * 3 + s1) * 64 + q * 8;
            const unsigned short* bp0 = L3o + ((2 * n4) * 16 + c) * 72 + q * 8;
            const unsigned short* bp1 = L3o + ((2 * n4 + 1) * 16 + c) * 72 + q * 8;
            f32x4 acc0 = {0.f,0.f,0.f,0.f}, acc1 = {0.f,0.f,0.f,0.f};
            mfma_tile<64>(a0, a1, bp0, bp1, acc0, acc1);
            epilogue_store(L4o + (n4 * 16 + c) * 72 + f0 + q * 4,
                           acc0, acc1, B4, f0 + q * 4, s0, s1);
        }
    }
    __syncthreads();

    // ---- L5 (cf=64, cin=64): 4 pos x 4 ftiles = 16 tasks ----
    {
        const unsigned short* L4o = (const unsigned short*)(arena + A_L4O);
        unsigned short* L5o = (unsigned short*)(arena + A_L5O);
        const int* S5 = P.Sl[2]; const float* B5 = P.Bl[2];
        for (int t = wv; t < 16; t += 8) {
            int n5 = t >> 2, ft = t & 3;
            int np = sl * 4 + n5;
            int s0 = __builtin_amdgcn_readfirstlane(S5[2 * np]);
            int s1 = __builtin_amdgcn_readfirstlane(S5[2 * np + 1]);
            int f0 = ft * 16;
            const unsigned short* a0 = W5b + ((f0 + c) * 3 + s0) * 64 + q * 8;
            const unsigned short* a1 = W5b + ((f0 + c) * 3 + s1) * 64 + q * 8;
            const unsigned short* bp0 = L4o + ((2 * n5) * 16 + c) * 72 + q * 8;
            const unsigned short* bp1 = L4o + ((2 * n5 + 1) * 16 + c) * 72 + q * 8;
            f32x4 acc0 = {0.f,0.f,0.f,0.f}, acc1 = {0.f,0.f,0.f,0.f};
            mfma_tile<64>(a0, a1, bp0, bp1, acc0, acc1);
            epilogue_store(L5o + (n5 * 16 + c) * 72 + f0 + q * 4,
                           acc0, acc1, B5, f0 + q * 4, s0, s1);
        }
    }
    __syncthreads();

    // ---- L6 (cf=128, cin=64): 2 pos x 8 ftiles = 16 tasks ----
    {
        const unsigned short* L5o = (const unsigned short*)(arena + A_L5O);
        unsigned short* L6o = (unsigned short*)(arena + A_L6O);
        const int* S6 = P.Sl[3]; const float* B6 = P.Bl[3];
        for (int t = wv; t < 16; t += 8) {
            int n6 = t >> 3, ft = t & 7;
            int np = sl * 2 + n6;
            int s0 = __builtin_amdgcn_readfirstlane(S6[2 * np]);
            int s1 = __builtin_amdgcn_readfirstlane(S6[2 * np + 1]);
            int f0 = ft * 16;
            const unsigned short* a0 = W6b + ((f0 + c) * 3 + s0) * 64 + q * 8;
            const unsigned short* a1 = W6b + ((f0 + c) * 3 + s1) * 64 + q * 8;
            const unsigned short* bp0 = L5o + ((2 * n6) * 16 + c) * 72 + q * 8;
            const unsigned short* bp1 = L5o + ((2 * n6 + 1) * 16 + c) * 72 + q * 8;
            f32x4 acc0 = {0.f,0.f,0.f,0.f}, acc1 = {0.f,0.f,0.f,0.f};
            mfma_tile<64>(a0, a1, bp0, bp1, acc0, acc1);
            epilogue_store(L6o + (n6 * 16 + c) * 136 + f0 + q * 4,
                           acc0, acc1, B6, f0 + q * 4, s0, s1);
        }
    }
    __syncthreads();

    // ---- L7 (cf=256, cin=128): 1 pos x 16 ftiles; A from packed global bf16 ----
    {
        const unsigned short* L6o = (const unsigned short*)(arena + A_L6O);
        const int* S7 = P.Sl[4]; const float* B7 = P.Bl[4];
        int s0 = __builtin_amdgcn_readfirstlane(S7[2 * sl]);
        int s1 = __builtin_amdgcn_readfirstlane(S7[2 * sl + 1]);
#pragma unroll 2
        for (int t = wv; t < 16; t += 8) {
            int f0 = t * 16;
            const unsigned short* a0 = W7b + (size_t)((f0 + c) * 3 + s0) * 128 + q * 8;
            const unsigned short* a1 = W7b + (size_t)((f0 + c) * 3 + s1) * 128 + q * 8;
            const unsigned short* bp0 = L6o + (0 * 16 + c) * 136 + q * 8;
            const unsigned short* bp1 = L6o + (1 * 16 + c) * 136 + q * 8;
            f32x4 acc0 = {0.f,0.f,0.f,0.f}, acc1 = {0.f,0.f,0.f,0.f};
            mfma_tile<128>(a0, a1, bp0, bp1, acc0, acc1);
            epilogue_store(P.X8 + ((size_t)sl * 128 + bg * 16 + c) * 256 + f0 + q * 4,
                           acc0, acc1, B7, f0 + q * 4, s0, s1);
        }
    }
}

// ============================================================================
// Flat MFMA layer (L8..L11): verified R9 body (R0 verbatim).
// ============================================================================
template<int CIN, int CF, int NP, int MW, int NW>
__global__ __launch_bounds__(256) void mfma_kernel(
    const unsigned short* __restrict__ Xin,
    const unsigned short* __restrict__ Wb,
    const float* __restrict__ bias,
    const int*   __restrict__ sel,
    unsigned short* __restrict__ Xout)
{
    constexpr int FT = CF / (16 * MW);
    constexpr int BT = 128 / (16 * NW);

    const int wid  = threadIdx.x >> 6;
    const int lane = threadIdx.x & 63;
    const int task = blockIdx.x * 4 + wid;
    const int bi = task % BT;
    const int fi = (task / BT) % FT;
    const int n  = task / (BT * FT);

    const int c = lane & 15;
    const int q = lane >> 4;
    const int s0 = __builtin_amdgcn_readfirstlane(sel[2 * n]);
    const int s1 = __builtin_amdgcn_readfirstlane(sel[2 * n + 1]);

    const int f0 = fi * 16 * MW;
    const int b0 = bi * 16 * NW;

    const unsigned short* ap[2][MW];
    const unsigned short* bp[2][NW];
#pragma unroll
    for (int p = 0; p < 2; ++p) {
        int s = p ? s1 : s0;
#pragma unroll
        for (int mi = 0; mi < MW; ++mi)
            ap[p][mi] = Wb + (size_t)((f0 + mi * 16 + c) * 3 + s) * CIN + q * 8;
#pragma unroll
        for (int ni = 0; ni < NW; ++ni)
            bp[p][ni] = Xin + ((size_t)(2 * n + p) * 128 + b0 + ni * 16 + c) * CIN + q * 8;
    }

    f32x4 acc[2][MW][NW];
#pragma unroll
    for (int p = 0; p < 2; ++p)
#pragma unroll
        for (int mi = 0; mi < MW; ++mi)
#pragma unroll
            for (int ni = 0; ni < NW; ++ni)
                acc[p][mi][ni] = (f32x4){0.f, 0.f, 0.f, 0.f};

#pragma unroll 2
    for (int k = 0; k < CIN; k += 32) {
        bf16x8 A[2][MW], B[2][NW];
#pragma unroll
        for (int p = 0; p < 2; ++p) {
#pragma unroll
            for (int mi = 0; mi < MW; ++mi)
                A[p][mi] = __builtin_bit_cast(bf16x8, *(const float4*)(const void*)(ap[p][mi] + k));
#pragma unroll
            for (int ni = 0; ni < NW; ++ni)
                B[p][ni] = __builtin_bit_cast(bf16x8, *(const float4*)(const void*)(bp[p][ni] + k));
        }
#pragma unroll
        for (int p = 0; p < 2; ++p)
#pragma unroll
            for (int mi = 0; mi < MW; ++mi)
#pragma unroll
                for (int ni = 0; ni < NW; ++ni)
                    acc[p][mi][ni] = __builtin_amdgcn_mfma_f32_16x16x32_bf16(
                        A[p][mi], B[p][ni], acc[p][mi][ni], 0, 0, 0);
    }

#pragma unroll
    for (int mi = 0; mi < MW; ++mi) {
        int fbase = f0 + mi * 16 + q * 4;
#pragma unroll
        for (int ni = 0; ni < NW; ++ni) {
            int b = b0 + ni * 16 + c;
            epilogue_store(Xout + ((size_t)n * 128 + b) * CF + fbase,
                           acc[0][mi][ni], acc[1][mi][ni], bias, fbase, s0, s1);
        }
    }
}

// ============================================================================
// FC head: h bf16 [128][1024]; out [128][16] fp32 log-softmax (R0 verbatim)
// ============================================================================
__global__ __launch_bounds__(256) void fc_logsoftmax_kernel(
    const unsigned short* __restrict__ h, const float* __restrict__ fcW,
    const float* __restrict__ fcb, float* __restrict__ out)
{
    int b   = blockIdx.x;
    int tid = threadIdx.x;
    int k     = tid & 15;
    int chunk = tid >> 4;

    const float* __restrict__ wk = fcW + (size_t)k * 1024;
    const unsigned short* hb = h + (size_t)b * 1024;

    float partial = 0.0f;
    int j0 = chunk * 64;
#pragma unroll 8
    for (int j = 0; j < 64; ++j)
        partial = fmaf(bf2f(hb[j0 + j]), wk[j0 + j], partial);

    __shared__ float red[16][17];
    red[chunk][k] = partial;
    __syncthreads();

    __shared__ float logits[16];
    if (tid < 16) {
        float s = fcb[tid];
#pragma unroll
        for (int c = 0; c < 16; ++c) s += red[c][tid];
        logits[tid] = s;
    }
    __syncthreads();

    if (tid < 16) {
        float mx = -INFINITY;
#pragma unroll
        for (int kk = 0; kk < 16; ++kk) mx = fmaxf(mx, logits[kk]);
        float se = 0.0f;
#pragma unroll
        for (int kk = 0; kk < 16; ++kk) se += expf(logits[kk] - mx);
        out[b * 16 + tid] = logits[tid] - mx - logf(se);
    }
}

// ============================================================================
extern "C" void kernel_launch(void* const* d_in, const int* in_sizes, int n_in,
                              void* d_out, int out_size, void* d_ws, size_t ws_size,
                              hipStream_t stream)
{
#define WL(i) (const float*)d_in[1 + 3 * (i)]
#define BL(i) (const float*)d_in[2 + 3 * (i)]
#define SL(i) (const int*)  d_in[3 + 3 * (i)]

    unsigned short* bufA = (unsigned short*)d_ws;          // 4 MB
    unsigned short* bufB = bufA + 2u * 1024u * 1024u;      // 4 MB
    unsigned short* Wb   = bufB + 2u * 1024u * 1024u;      // packed bf16 W3..W11

    // ---- K0: pack W3..W11 -> Wb ----
    PackParams PP;
    for (int i = 0; i < 9; ++i) PP.Wsrc[i] = WL(2 + i);
    PP.Wb = Wb;
    pack_w_kernel<<<256, 256, 0, stream>>>(PP);

    // ---- K1: fused L1..L7 -> X8 (bufA) ----
    FusedParams FP;
    FP.x  = (const float*)d_in[0];
    FP.W1 = WL(0); FP.B1 = BL(0); FP.S1 = SL(0);
    FP.W2 = WL(1); FP.B2 = BL(1); FP.S2 = SL(1);
    for (int i = 0; i < 9; ++i) {
        FP.Bl[i] = BL(2 + i);
        FP.Sl[i] = SL(2 + i);
    }
    FP.Wb = Wb; FP.X8 = bufA;
    fused17_kernel<<<128, 512, 0, stream>>>(FP);

    // ---- K2..K5: flat MFMA layers L8..L11 (R0-verified configs) ----
    mfma_kernel<256, 512, 8, 2, 2><<<128, 256, 0, stream>>>(bufA, Wb + O_W8,  BL(7),  SL(7),  bufB);
    mfma_kernel<512, 512, 4, 1, 1><<<256, 256, 0, stream>>>(bufB, Wb + O_W9,  BL(8),  SL(8),  bufA);
    mfma_kernel<512, 512, 2, 1, 1><<<128, 256, 0, stream>>>(bufA, Wb + O_W10, BL(9),  SL(9),  bufB);
    mfma_kernel<512, 1024, 1, 1, 1><<<128, 256, 0, stream>>>(bufB, Wb + O_W11, BL(10), SL(10), bufA);

    // ---- K6: FC ----
    fc_logsoftmax_kernel<<<128, 256, 0, stream>>>(bufA, (const float*)d_in[34], (const float*)d_in[35], (float*)d_out);

#undef WL
#undef BL
#undef SL
}